// Round 1
// baseline (547.278 us; speedup 1.0000x reference)
//
#include <hip/hip_runtime.h>
#include <cstdint>

// ---------------------------------------------------------------------------
// WindowAttention (Swin): B_WIN=4096 windows, N=49 tokens, DIM=256, HEADS=8,
// head_dim=32, NW=64 masks.
// Pipeline: cvt_x -> cvt_w -> comb -> qkv gemm -> attention -> proj gemm.
// All bf16 MFMA (16x16x32), fp32 accumulate.
// ---------------------------------------------------------------------------

typedef __attribute__((ext_vector_type(8))) short short8;   // bf16x8 frag (4 VGPR)
typedef __attribute__((ext_vector_type(4))) float floatx4;  // fp32x4 acc frag

__device__ __forceinline__ ushort f2bf(float f) {
    uint32_t u = __float_as_uint(f);
    u += 0x7FFFu + ((u >> 16) & 1u);   // RNE
    return (ushort)(u >> 16);
}

__device__ __forceinline__ void gl_lds16(const ushort* g, ushort* lds) {
    __builtin_amdgcn_global_load_lds(
        (const __attribute__((address_space(1))) uint32_t*)g,
        (__attribute__((address_space(3))) uint32_t*)lds, 16, 0, 0);
}

// ---------------------------------------------------------------- kernel 0a
__global__ __launch_bounds__(256) void k_cvt_x(const float* __restrict__ x,
                                               ushort* __restrict__ xb, int n4) {
    int i = blockIdx.x * blockDim.x + threadIdx.x;
    const int stride = gridDim.x * blockDim.x;
    const float4* x4 = (const float4*)x;
    ushort4* o4 = (ushort4*)xb;
    for (; i < n4; i += stride) {
        float4 v = x4[i];
        ushort4 o;
        o.x = f2bf(v.x); o.y = f2bf(v.y); o.z = f2bf(v.z); o.w = f2bf(v.w);
        o4[i] = o;
    }
}

// ---------------------------------------------------------------- kernel 0b
// qkv_w: 768*256 = 196608 elems; proj_w: 256*256 = 65536. grid 1024 x 256.
__global__ __launch_bounds__(256) void k_cvt_w(const float* __restrict__ qw,
                                               const float* __restrict__ pw,
                                               ushort* __restrict__ qwb,
                                               ushort* __restrict__ pwb) {
    int i = blockIdx.x * 256 + threadIdx.x;
    if (i < 196608) qwb[i] = f2bf(qw[i]);
    else            pwb[i - 196608] = f2bf(pw[i - 196608]);
}

// ---------------------------------------------------------------- kernel 0c
// comb[w][h][n][m] = mask[w][n][m] + bias_table[rel_index[n][m]][h]
// grid = 512 blocks (w*8+h), 256 threads.
__global__ __launch_bounds__(256) void k_comb(const float* __restrict__ mask,
                                              const int* __restrict__ rel,
                                              const float* __restrict__ bt,
                                              float* __restrict__ comb) {
    const int wh = blockIdx.x;
    const int w = wh >> 3, h = wh & 7;
    const float* mw = mask + (size_t)w * 2401;
    float* out = comb + (size_t)wh * 2401;
    for (int e = threadIdx.x; e < 2401; e += 256)
        out[e] = mw[e] + bt[rel[e] * 8 + h];
}

// ---------------------------------------------------------------- kernel 1
// qkv gemm_bt: C[tok][c] = sum_k xb[tok][k]*qkv_w[c][k] + qkv_b[c]
// M=200704 (=1568*128), N=768 (=6*128), K=256. BM=BN=128, BK=32.
// Epilogue scatters to q/k/v ws arrays: [(b*8+h)][n(49)][dd(32)] bf16.
__global__ __launch_bounds__(256) void k_qkv(const ushort* __restrict__ xb,
                                             const ushort* __restrict__ wb,
                                             const float* __restrict__ qb,
                                             ushort* __restrict__ qws,
                                             ushort* __restrict__ kws,
                                             ushort* __restrict__ vws) {
    __shared__ ushort As[128 * 32];
    __shared__ ushort Bs[128 * 32];
    const int bid = blockIdx.x;
    const int bn = bid % 6, bm = bid / 6;  // consecutive blocks share A-tile
    const int t = threadIdx.x;
    const int l = t & 63, w = t >> 6;
    const int wm = w >> 1, wn = w & 1;

    const ushort* Ag = xb + (size_t)bm * 128 * 256;
    const ushort* Bg = wb + (size_t)bn * 128 * 256;

    const floatx4 zf = {0.f, 0.f, 0.f, 0.f};
    floatx4 acc[4][4];
#pragma unroll
    for (int i = 0; i < 4; ++i)
#pragma unroll
        for (int j = 0; j < 4; ++j) acc[i][j] = zf;

    const int srow = t >> 2;            // 0..63
    const int scol = (t & 3) * 8;       // 0,8,16,24
    const int aoff = (wm * 64 + (l & 15)) * 32 + (l >> 4) * 8;
    const int boff = (wn * 64 + (l & 15)) * 32 + (l >> 4) * 8;

    for (int kt = 0; kt < 8; ++kt) {
#pragma unroll
        for (int i = 0; i < 2; ++i) {
            gl_lds16(Ag + (size_t)(i * 64 + srow) * 256 + kt * 32 + scol,
                     As + i * 2048 + w * 512);
            gl_lds16(Bg + (size_t)(i * 64 + srow) * 256 + kt * 32 + scol,
                     Bs + i * 2048 + w * 512);
        }
        __syncthreads();
        short8 af[4], bfr[4];
#pragma unroll
        for (int mt = 0; mt < 4; ++mt) af[mt] = *(const short8*)(As + aoff + mt * 512);
#pragma unroll
        for (int nt = 0; nt < 4; ++nt) bfr[nt] = *(const short8*)(Bs + boff + nt * 512);
#pragma unroll
        for (int mt = 0; mt < 4; ++mt)
#pragma unroll
            for (int nt = 0; nt < 4; ++nt)
                acc[mt][nt] = __builtin_amdgcn_mfma_f32_16x16x32_bf16(
                    af[mt], bfr[nt], acc[mt][nt], 0, 0, 0);
        __syncthreads();
    }

#pragma unroll
    for (int nt = 0; nt < 4; ++nt) {
        const int c = bn * 128 + wn * 64 + nt * 16 + (l & 15);
        const int which = c >> 8, hd = (c >> 5) & 7, dd = c & 31;
        const float bias = qb[c];
        ushort* dst = which == 0 ? qws : (which == 1 ? kws : vws);
#pragma unroll
        for (int mt = 0; mt < 4; ++mt)
#pragma unroll
            for (int r = 0; r < 4; ++r) {
                const int tok = bm * 128 + wm * 64 + mt * 16 + (l >> 4) * 4 + r;
                const int b = tok / 49;
                const int n = tok - b * 49;
                dst[(size_t)(b * 8 + hd) * 1568 + n * 32 + dd] =
                    f2bf(acc[mt][nt][r] + bias);
            }
    }
}

// ---------------------------------------------------------------- kernel 2
// Attention: one wave per (b,h) = bh in [0,32768). 2 waves / 128-thr block.
// Per-wave LDS region (24640 B): P [64][72] bf16 | vT [32][72] bf16 |
// S [51][53] fp32 (row 49 holds 1/sum).
__global__ __launch_bounds__(128) void k_attn(const ushort* __restrict__ qws,
                                              const ushort* __restrict__ kws,
                                              const ushort* __restrict__ vws,
                                              const float* __restrict__ comb,
                                              ushort* __restrict__ ao) {
    __shared__ __align__(16) char smem[2 * 24640];
    const int wid = threadIdx.x >> 6;
    const int l = threadIdx.x & 63;
    const int bh = blockIdx.x * 2 + wid;
    const int b = bh >> 3, h = bh & 7, w = b & 63;

    ushort* P  = (ushort*)(smem + wid * 24640);           // [64][72]
    ushort* vT = (ushort*)(smem + wid * 24640 + 9216);    // [32][72]
    float*  S  = (float*)(smem + wid * 24640 + 13824);    // [51][53]

    const ushort* qg = qws + (size_t)bh * 1568;
    const ushort* kg = kws + (size_t)bh * 1568;
    const ushort* vg = vws + (size_t)bh * 1568;

    // --- Q/K fragments straight from global (coalesced 1KB per mt) ---
    const int kq = (l >> 4) * 8;
    const short8 z8 = {0, 0, 0, 0, 0, 0, 0, 0};
    short8 qf[4], kf[4];
#pragma unroll
    for (int mt = 0; mt < 4; ++mt) {
        const int n = mt * 16 + (l & 15);
        qf[mt] = (n < 49) ? *(const short8*)(qg + n * 32 + kq) : z8;
        kf[mt] = (n < 49) ? *(const short8*)(kg + n * 32 + kq) : z8;
    }

    // --- stage V transposed into LDS: vT[dd][m], m = lane, zero-pad m>=49 ---
    uint4 vv[4];
    if (l < 49) {
#pragma unroll
        for (int i = 0; i < 4; ++i) vv[i] = *(const uint4*)(vg + (size_t)l * 32 + i * 8);
    } else {
#pragma unroll
        for (int i = 0; i < 4; ++i) vv[i] = make_uint4(0u, 0u, 0u, 0u);
    }
#pragma unroll
    for (int i = 0; i < 4; ++i) {
        const uint32_t uu[4] = {vv[i].x, vv[i].y, vv[i].z, vv[i].w};
#pragma unroll
        for (int j = 0; j < 4; ++j) {
            const int dd = i * 8 + j * 2;
            vT[dd * 72 + l]       = (ushort)(uu[j] & 0xFFFFu);
            vT[(dd + 1) * 72 + l] = (ushort)(uu[j] >> 16);
        }
    }

    // --- S = scale * Q K^T + comb ---
    const floatx4 zf = {0.f, 0.f, 0.f, 0.f};
    floatx4 sac[4][4];
#pragma unroll
    for (int mt = 0; mt < 4; ++mt)
#pragma unroll
        for (int nt = 0; nt < 4; ++nt)
            sac[mt][nt] = __builtin_amdgcn_mfma_f32_16x16x32_bf16(qf[mt], kf[nt], zf, 0, 0, 0);

    const float* cw = comb + (size_t)(w * 8 + h) * 2401;
    const float scale = 0.17677669529663687f;  // 32^-0.5
#pragma unroll
    for (int mt = 0; mt < 4; ++mt) {
        const int n0 = mt * 16 + (l >> 4) * 4;
#pragma unroll
        for (int nt = 0; nt < 4; ++nt) {
            const int m = nt * 16 + (l & 15);
#pragma unroll
            for (int r = 0; r < 4; ++r) {
                const int n = n0 + r;
                if (n < 49 && m < 49)
                    S[n * 53 + m] = sac[mt][nt][r] * scale + cw[n * 49 + m];
            }
        }
    }

    // --- per-row softmax (lane r handles row r); P bf16 (un-normalized) ---
    const int r = l;
    const bool act = r < 49;
    const float* Srow = S + r * 53;
    float mx = -1e30f;
    if (act) {
        float m0 = Srow[48], m1 = -1e30f, m2 = -1e30f, m3 = -1e30f;
#pragma unroll
        for (int m = 0; m < 48; m += 4) {
            m0 = fmaxf(m0, Srow[m]);
            m1 = fmaxf(m1, Srow[m + 1]);
            m2 = fmaxf(m2, Srow[m + 2]);
            m3 = fmaxf(m3, Srow[m + 3]);
        }
        mx = fmaxf(fmaxf(m0, m1), fmaxf(m2, m3));
    }
    float sum0 = 0.f, sum1 = 0.f;
    uint32_t* P32 = (uint32_t*)(P + r * 72);
#pragma unroll
    for (int m = 0; m < 64; m += 2) {
        float p0 = 0.f, p1 = 0.f;
        if (act && m < 49)     { p0 = __expf(Srow[m] - mx);     sum0 += p0; }
        if (act && m + 1 < 49) { p1 = __expf(Srow[m + 1] - mx); sum1 += p1; }
        P32[m >> 1] = (uint32_t)f2bf(p0) | ((uint32_t)f2bf(p1) << 16);
    }
    S[49 * 53 + r] = act ? 1.f / (sum0 + sum1) : 0.f;

    // --- O = P V ---
    floatx4 oac[4][2];
#pragma unroll
    for (int mt = 0; mt < 4; ++mt)
#pragma unroll
        for (int nt = 0; nt < 2; ++nt) oac[mt][nt] = zf;
#pragma unroll
    for (int ks = 0; ks < 2; ++ks) {
        short8 vf[2];
#pragma unroll
        for (int nt = 0; nt < 2; ++nt) {
            const int dd = nt * 16 + (l & 15);
            vf[nt] = *(const short8*)(vT + dd * 72 + ks * 32 + (l >> 4) * 8);
        }
#pragma unroll
        for (int mt = 0; mt < 4; ++mt) {
            const int n = mt * 16 + (l & 15);
            const short8 pf = *(const short8*)(P + n * 72 + ks * 32 + (l >> 4) * 8);
#pragma unroll
            for (int nt = 0; nt < 2; ++nt)
                oac[mt][nt] = __builtin_amdgcn_mfma_f32_16x16x32_bf16(pf, vf[nt], oac[mt][nt], 0, 0, 0);
        }
    }

    // --- normalize + store: ao[(b*49+n)*256 + h*32 + dd] ---
    ushort* og = ao + (size_t)b * 49 * 256 + h * 32;
#pragma unroll
    for (int mt = 0; mt < 4; ++mt) {
        const int n0 = mt * 16 + (l >> 4) * 4;
#pragma unroll
        for (int rr = 0; rr < 4; ++rr) {
            const int n = n0 + rr;
            if (n < 49) {
                const float rs = S[49 * 53 + n];
#pragma unroll
                for (int nt = 0; nt < 2; ++nt) {
                    const int dd = nt * 16 + (l & 15);
                    og[(size_t)n * 256 + dd] = f2bf(oac[mt][nt][rr] * rs);
                }
            }
        }
    }
}

// ---------------------------------------------------------------- kernel 3
// proj gemm_bt: out[tok][c] = sum_k ao[tok][k]*proj_w[c][k] + proj_b[c]
// M=200704, N=256 (=2*128), K=256. fp32 output.
__global__ __launch_bounds__(256) void k_proj(const ushort* __restrict__ ab,
                                              const ushort* __restrict__ wb,
                                              const float* __restrict__ pb,
                                              float* __restrict__ out) {
    __shared__ ushort As[128 * 32];
    __shared__ ushort Bs[128 * 32];
    const int bid = blockIdx.x;
    const int bn = bid & 1, bm = bid >> 1;
    const int t = threadIdx.x;
    const int l = t & 63, w = t >> 6;
    const int wm = w >> 1, wn = w & 1;

    const ushort* Ag = ab + (size_t)bm * 128 * 256;
    const ushort* Bg = wb + (size_t)bn * 128 * 256;

    const floatx4 zf = {0.f, 0.f, 0.f, 0.f};
    floatx4 acc[4][4];
#pragma unroll
    for (int i = 0; i < 4; ++i)
#pragma unroll
        for (int j = 0; j < 4; ++j) acc[i][j] = zf;

    const int srow = t >> 2;
    const int scol = (t & 3) * 8;
    const int aoff = (wm * 64 + (l & 15)) * 32 + (l >> 4) * 8;
    const int boff = (wn * 64 + (l & 15)) * 32 + (l >> 4) * 8;

    for (int kt = 0; kt < 8; ++kt) {
#pragma unroll
        for (int i = 0; i < 2; ++i) {
            gl_lds16(Ag + (size_t)(i * 64 + srow) * 256 + kt * 32 + scol,
                     As + i * 2048 + w * 512);
            gl_lds16(Bg + (size_t)(i * 64 + srow) * 256 + kt * 32 + scol,
                     Bs + i * 2048 + w * 512);
        }
        __syncthreads();
        short8 af[4], bfr[4];
#pragma unroll
        for (int mt = 0; mt < 4; ++mt) af[mt] = *(const short8*)(As + aoff + mt * 512);
#pragma unroll
        for (int nt = 0; nt < 4; ++nt) bfr[nt] = *(const short8*)(Bs + boff + nt * 512);
#pragma unroll
        for (int mt = 0; mt < 4; ++mt)
#pragma unroll
            for (int nt = 0; nt < 4; ++nt)
                acc[mt][nt] = __builtin_amdgcn_mfma_f32_16x16x32_bf16(
                    af[mt], bfr[nt], acc[mt][nt], 0, 0, 0);
        __syncthreads();
    }

#pragma unroll
    for (int nt = 0; nt < 4; ++nt) {
        const int c = bn * 128 + wn * 64 + nt * 16 + (l & 15);
        const float bias = pb[c];
#pragma unroll
        for (int mt = 0; mt < 4; ++mt)
#pragma unroll
            for (int r = 0; r < 4; ++r) {
                const int tok = bm * 128 + wm * 64 + mt * 16 + (l >> 4) * 4 + r;
                out[(size_t)tok * 256 + c] = acc[mt][nt][r] + bias;
            }
    }
}

// ---------------------------------------------------------------------------
extern "C" void kernel_launch(void* const* d_in, const int* in_sizes, int n_in,
                              void* d_out, int out_size, void* d_ws, size_t ws_size,
                              hipStream_t stream) {
    const float* x      = (const float*)d_in[0];
    const float* mask   = (const float*)d_in[1];
    const int*   rel    = (const int*)d_in[2];
    const float* qkv_w  = (const float*)d_in[3];
    const float* qkv_b  = (const float*)d_in[4];
    const float* proj_w = (const float*)d_in[5];
    const float* proj_b = (const float*)d_in[6];
    const float* bt     = (const float*)d_in[7];
    float* out = (float*)d_out;

    // ws layout (bytes); total = 519,243,776 (~495 MiB)
    char* ws = (char*)d_ws;
    ushort* xb   = (ushort*)(ws);                  // 200704*256 bf16
    ushort* qwb  = (ushort*)(ws + 102760448);      // 768*256 bf16
    ushort* pwb  = (ushort*)(ws + 103153664);      // 256*256 bf16
    float*  comb = (float*) (ws + 103284736);      // 64*8*2401 f32
    ushort* qws  = (ushort*)(ws + 108201984);      // 32768*49*32 bf16
    ushort* kws  = (ushort*)(ws + 210962432);
    ushort* vws  = (ushort*)(ws + 313722880);
    ushort* aob  = (ushort*)(ws + 416483328);      // 200704*256 bf16
    (void)ws_size; (void)in_sizes; (void)n_in; (void)out_size;

    k_cvt_x<<<dim3(2048), dim3(256), 0, stream>>>(x, xb, 12845056);
    k_cvt_w<<<dim3(1024), dim3(256), 0, stream>>>(qkv_w, proj_w, qwb, pwb);
    k_comb <<<dim3(512),  dim3(256), 0, stream>>>(mask, rel, bt, comb);
    k_qkv  <<<dim3(9408), dim3(256), 0, stream>>>(xb, qwb, qkv_b, qws, kws, vws);
    k_attn <<<dim3(16384), dim3(128), 0, stream>>>(qws, kws, vws, comb, aob);
    k_proj <<<dim3(3136), dim3(256), 0, stream>>>(aob, pwb, proj_b, out);
}